// Round 8
// baseline (254.550 us; speedup 1.0000x reference)
//
#include <hip/hip_runtime.h>
#include <hip/hip_bf16.h>

#define NN 2048
#define FF 64
#define NH 8
#define BDIM 4
#define BH 32        // BDIM*NH

typedef __attribute__((ext_vector_type(8))) short short8;
typedef __attribute__((ext_vector_type(4))) float floatx4;
typedef __attribute__((ext_vector_type(4))) unsigned uint4v;

__device__ __forceinline__ float LDIN(const void* p, size_t i, int b16) {
    return b16 ? __bfloat162float(((const __hip_bfloat16*)p)[i]) : ((const float*)p)[i];
}
__device__ __forceinline__ void split2(float x, ushort& hi, ushort& lo) {
    unsigned u = __float_as_uint(x);
    hi = (ushort)(u >> 16);
    float fl = x - __uint_as_float(u & 0xFFFF0000u);
    lo = (ushort)(__float_as_uint(fl) >> 16);
}
__device__ __forceinline__ ushort bf16bits(float v) {
    __hip_bfloat16 b = __float2bfloat16(v);
    return __builtin_bit_cast(ushort, b);
}

// ---- Kernel 1: MFMA GEMM hp=h@w; writes hpT (transposed bf16), exp factors --
// grid 1024: block = (b, hd, 64-row tile). 256 thr = 4 waves.
__global__ __launch_bounds__(256) void k_proj(
    const void* __restrict__ h, const void* __restrict__ w,
    const void* __restrict__ asrc, const void* __restrict__ adst,
    ushort* __restrict__ hpT, float* __restrict__ esHa, float* __restrict__ esLa,
    float* __restrict__ edHa, float* __restrict__ edLa, int* __restrict__ flagOut)
{
    const int t  = threadIdx.x;
    const int rt = blockIdx.x & 31;
    const int hd = (blockIdx.x >> 5) & 7;
    const int b  = blockIdx.x >> 8;
    const int bh = b * NH + hd;
    const int r0 = rt * 64;

    __shared__ int sb16;
    if (t < 64) {
        unsigned word = ((const unsigned*)h)[t];
        unsigned lowexp = (word >> 7) & 0xFFu;
        bool plaus = (lowexp >= 96u && lowexp <= 159u);
        unsigned long long m = __ballot(plaus);
        if (t == 0) sb16 = (__popcll(m) >= 48) ? 1 : 0;
    }
    __shared__ ushort bHi[64 * 72];     // transposed w: bHi[n][k], stride 72
    __shared__ ushort bLo[64 * 72];
    __shared__ ushort trans[64 * 72];   // hp^T tile: trans[o][i_local]
    __syncthreads();
    const int b16 = sb16;
    if (blockIdx.x == 0 && t == 0) flagOut[0] = b16;

    if (b16) {
        const ushort* wp = (const ushort*)w + (size_t)hd * FF * FF;
        for (int e4 = t; e4 < 1024; e4 += 256) {
            uint2 u = *(const uint2*)(wp + e4 * 4);
            int e = e4 * 4, k = e >> 6, n = e & 63;
            bHi[(n + 0) * 72 + k] = (ushort)(u.x & 0xFFFF);
            bHi[(n + 1) * 72 + k] = (ushort)(u.x >> 16);
            bHi[(n + 2) * 72 + k] = (ushort)(u.y & 0xFFFF);
            bHi[(n + 3) * 72 + k] = (ushort)(u.y >> 16);
        }
    } else {
        const float* wp = (const float*)w + (size_t)hd * FF * FF;
        for (int e4 = t; e4 < 1024; e4 += 256) {
            floatx4 x = *(const floatx4*)(wp + e4 * 4);
            int e = e4 * 4, k = e >> 6, n = e & 63;
#pragma unroll
            for (int r = 0; r < 4; ++r) {
                ushort hi, lo; split2(x[r], hi, lo);
                bHi[(n + r) * 72 + k] = hi;
                bLo[(n + r) * 72 + k] = lo;
            }
        }
    }
    __syncthreads();

    const int wv = t >> 6, lane = t & 63;
    const int ml = lane & 15, q = lane >> 4;
    const int grow = b * NN + r0 + wv * 16 + ml;

    short8 ah[2], al[2];
    if (b16) {
        const ushort* hp16 = (const ushort*)h;
#pragma unroll
        for (int kc = 0; kc < 2; ++kc) {
            uint4v u = *(const uint4v*)(hp16 + (size_t)grow * FF + kc * 32 + q * 8);
            ah[kc] = __builtin_bit_cast(short8, u);
        }
    } else {
        const float* hpf = (const float*)h;
#pragma unroll
        for (int kc = 0; kc < 2; ++kc) {
            floatx4 x0 = *(const floatx4*)(hpf + (size_t)grow * FF + kc * 32 + q * 8);
            floatx4 x1 = *(const floatx4*)(hpf + (size_t)grow * FF + kc * 32 + q * 8 + 4);
            short8 H, L;
#pragma unroll
            for (int r = 0; r < 4; ++r) {
                ushort hi, lo;
                split2(x0[r], hi, lo); H[r] = (short)hi; L[r] = (short)lo;
                split2(x1[r], hi, lo); H[4 + r] = (short)hi; L[4 + r] = (short)lo;
            }
            ah[kc] = H; al[kc] = L;
        }
    }

    short8 bhf[4][2], blf[4][2];
#pragma unroll
    for (int nt = 0; nt < 4; ++nt)
#pragma unroll
        for (int kc = 0; kc < 2; ++kc) {
            int n = nt * 16 + ml, k = kc * 32 + q * 8;
            bhf[nt][kc] = *(const short8*)&bHi[n * 72 + k];
            if (!b16) blf[nt][kc] = *(const short8*)&bLo[n * 72 + k];
        }

    float aS[4], aD[4];
#pragma unroll
    for (int nt = 0; nt < 4; ++nt) {
        aS[nt] = LDIN(asrc, hd * FF + nt * 16 + ml, b16);
        aD[nt] = LDIN(adst, hd * FF + nt * 16 + ml, b16);
    }

    floatx4 acc[4];
#pragma unroll
    for (int nt = 0; nt < 4; ++nt) {
        floatx4 a = {0.f, 0.f, 0.f, 0.f};
        if (b16) {
#pragma unroll
            for (int kc = 0; kc < 2; ++kc)
                a = __builtin_amdgcn_mfma_f32_16x16x32_bf16(ah[kc], bhf[nt][kc], a, 0, 0, 0);
        } else {
#pragma unroll
            for (int kc = 0; kc < 2; ++kc) {
                a = __builtin_amdgcn_mfma_f32_16x16x32_bf16(ah[kc], bhf[nt][kc], a, 0, 0, 0);
                a = __builtin_amdgcn_mfma_f32_16x16x32_bf16(ah[kc], blf[nt][kc], a, 0, 0, 0);
                a = __builtin_amdgcn_mfma_f32_16x16x32_bf16(al[kc], bhf[nt][kc], a, 0, 0, 0);
            }
        }
        acc[nt] = a;
    }

    float ps[4] = {0.f, 0.f, 0.f, 0.f}, pd[4] = {0.f, 0.f, 0.f, 0.f};
#pragma unroll
    for (int nt = 0; nt < 4; ++nt)
#pragma unroll
        for (int reg = 0; reg < 4; ++reg) {
            int il = wv * 16 + q * 4 + reg;          // C/D: row=q*4+reg, col=ml
            float v = acc[nt][reg];
            trans[(nt * 16 + ml) * 72 + il] = bf16bits(v);
            float tv = tanhf(v);
            ps[reg] += tv * aS[nt];
            pd[reg] += tv * aD[nt];
        }
#pragma unroll
    for (int msk = 1; msk < 16; msk <<= 1)
#pragma unroll
        for (int reg = 0; reg < 4; ++reg) {
            ps[reg] += __shfl_xor(ps[reg], msk, 64);
            pd[reg] += __shfl_xor(pd[reg], msk, 64);
        }
    if (ml == 0) {
#pragma unroll
        for (int reg = 0; reg < 4; ++reg) {
            int i = bh * NN + r0 + wv * 16 + q * 4 + reg;
            float sv = ps[reg], dv = pd[reg];
            esHa[i] = __expf(sv);
            esLa[i] = __expf(0.2f * sv);
            edHa[i] = __expf(dv);
            edLa[i] = __expf(0.2f * dv);
        }
    }
    __syncthreads();
    // coalesced transposed write-out: hpT[(bh*64+o)*NN + r0 + i_local]
    {
        const int o = t >> 2, icl = (t & 3) * 16;
        uint4v v0 = *(const uint4v*)&trans[o * 72 + icl];
        uint4v v1 = *(const uint4v*)&trans[o * 72 + icl + 8];
        ushort* dst = hpT + ((size_t)bh * 64 + o) * NN + r0 + icl;
        *(uint4v*)dst = v0;
        *(uint4v*)(dst + 8) = v1;
    }
}

// ---- Kernel 2: dense attention. p = max(es*edH, es2*edL), split-bf16 MFMA PV -
// grid 1024: block = (bh = blk&31, itile = blk>>5), 64 i-rows; wave = 1 M-tile.
__global__ __launch_bounds__(256) void k_attn(
    const ushort* __restrict__ hpT,
    const float* __restrict__ esHa, const float* __restrict__ esLa,
    const float* __restrict__ edHa, const float* __restrict__ edLa,
    const void* __restrict__ bias, const int* __restrict__ flag,
    void* __restrict__ out)
{
    const int b16 = flag[0];
    const int t = threadIdx.x;
    const int wv = t >> 6, lane = t & 63;
    const int ml = lane & 15, q = lane >> 4;
    const int bh = blockIdx.x & 31;
    const int i0 = (blockIdx.x >> 5) * 64;

    const ushort* Bb = hpT + (size_t)bh * 64 * NN;   // [o][j]
    const float* ehp = edHa + bh * NN;
    const float* elp = edLa + bh * NN;

    const int irow = i0 + wv * 16 + ml;              // this lane's A-row (P row)
    const float es  = esHa[bh * NN + irow];
    const float es2 = esLa[bh * NN + irow];

    floatx4 acc[4];
#pragma unroll
    for (int nt = 0; nt < 4; ++nt) acc[nt] = (floatx4){0.f, 0.f, 0.f, 0.f};
    float den = 0.f;

    short8 Bf[2][4];
    floatx4 eh[2][2], el[2][2];

    auto load = [&](int buf, int ks) {
        const int col = ks * 32 + q * 8;
#pragma unroll
        for (int nt = 0; nt < 4; ++nt) {
            uint4v u = *(const uint4v*)(Bb + (size_t)(nt * 16 + ml) * NN + col);
            Bf[buf][nt] = __builtin_bit_cast(short8, u);
        }
        eh[buf][0] = *(const floatx4*)(ehp + col);
        eh[buf][1] = *(const floatx4*)(ehp + col + 4);
        el[buf][0] = *(const floatx4*)(elp + col);
        el[buf][1] = *(const floatx4*)(elp + col + 4);
    };
    auto compute = [&](int cb) {
        float p[8];
#pragma unroll
        for (int j = 0; j < 4; ++j) {
            p[j]     = fmaxf(es * eh[cb][0][j], es2 * el[cb][0][j]);
            p[j + 4] = fmaxf(es * eh[cb][1][j], es2 * el[cb][1][j]);
        }
        den += ((p[0] + p[1]) + (p[2] + p[3])) + ((p[4] + p[5]) + (p[6] + p[7]));
        unsigned hw[4], lw[4];
#pragma unroll
        for (int pr = 0; pr < 4; ++pr) {
            unsigned u0 = __float_as_uint(p[2 * pr]);
            unsigned u1 = __float_as_uint(p[2 * pr + 1]);
            hw[pr] = __builtin_amdgcn_perm(u1, u0, 0x07060302);   // [u1_hi:u0_hi]
            float h0 = __uint_as_float(u0 & 0xFFFF0000u);
            float h1 = __uint_as_float(u1 & 0xFFFF0000u);
            lw[pr] = __builtin_amdgcn_perm(__float_as_uint(p[2 * pr + 1] - h1),
                                           __float_as_uint(p[2 * pr] - h0),
                                           0x07060302);
        }
        short8 PH = __builtin_bit_cast(short8, (uint4v){hw[0], hw[1], hw[2], hw[3]});
        short8 PL = __builtin_bit_cast(short8, (uint4v){lw[0], lw[1], lw[2], lw[3]});
#pragma unroll
        for (int nt = 0; nt < 4; ++nt) {
            acc[nt] = __builtin_amdgcn_mfma_f32_16x16x32_bf16(PH, Bf[cb][nt], acc[nt], 0, 0, 0);
            acc[nt] = __builtin_amdgcn_mfma_f32_16x16x32_bf16(PL, Bf[cb][nt], acc[nt], 0, 0, 0);
        }
    };

    load(0, 0);
    for (int ks = 0; ks < 64; ks += 2) {
        load(1, ks + 1);
        compute(0);
        if (ks + 2 < 64) load(0, ks + 2);
        compute(1);
    }

    // epilogue: reduce den over quads (rows ml), normalize, bias, store
    float biasv[4];
#pragma unroll
    for (int nt = 0; nt < 4; ++nt) biasv[nt] = LDIN(bias, nt * 16 + ml, b16);

    float d2 = den;
    d2 += __shfl_xor(d2, 16, 64);
    d2 += __shfl_xor(d2, 32, 64);                    // lanes now hold den[row=ml]
#pragma unroll
    for (int reg = 0; reg < 4; ++reg) {
        float dr = __shfl(d2, q * 4 + reg, 64);      // den for C/D row q*4+reg
        float inv = 1.0f / dr;
        int i = i0 + wv * 16 + q * 4 + reg;
#pragma unroll
        for (int nt = 0; nt < 4; ++nt) {
            float val = acc[nt][reg] * inv + biasv[nt];
            size_t oi = ((size_t)bh * NN + i) * FF + nt * 16 + ml;
            if (b16) ((__hip_bfloat16*)out)[oi] = __float2bfloat16(val);
            else     ((float*)out)[oi] = val;
        }
    }
}

extern "C" void kernel_launch(void* const* d_in, const int* in_sizes, int n_in,
                              void* d_out, int out_size, void* d_ws, size_t ws_size,
                              hipStream_t stream) {
    const void* h    = d_in[0];
    // d_in[1] = adj (bool) — unused by reference
    const void* w    = d_in[2];
    const void* asrc = d_in[3];
    const void* adst = d_in[4];
    const void* bias = d_in[5];

    float* ws = (float*)d_ws;
    int*    flag = (int*)ws;                          // 16 ints
    ushort* hpT  = (ushort*)(ws + 16);                // BH*64*NN bf16 (transposed)
    float*  esHa = (float*)(hpT + (size_t)BH * 64 * NN);  // BH*NN each
    float*  esLa = esHa + BH * NN;
    float*  edHa = esLa + BH * NN;
    float*  edLa = edHa + BH * NN;

    k_proj<<<BDIM * NH * 32, 256, 0, stream>>>(h, w, asrc, adst,
                                               hpT, esHa, esLa, edHa, edLa, flag);
    k_attn<<<BH * 32, 256, 0, stream>>>(hpT, esHa, esLa, edHa, edLa,
                                        bias, flag, d_out);
}

// Round 9
// 161.527 us; speedup vs baseline: 1.5759x; 1.5759x over previous
//
#include <hip/hip_runtime.h>
#include <hip/hip_bf16.h>

#define NN 2048
#define FF 64
#define NH 8
#define BDIM 4
#define BH 32        // BDIM*NH

typedef __attribute__((ext_vector_type(8))) short short8;
typedef __attribute__((ext_vector_type(4))) float floatx4;
typedef __attribute__((ext_vector_type(4))) unsigned uint4v;

__device__ __forceinline__ float LDIN(const void* p, size_t i, int b16) {
    return b16 ? __bfloat162float(((const __hip_bfloat16*)p)[i]) : ((const float*)p)[i];
}
// pack bf16(truncate) of f0 (low) and f1 (high) into one uint
__device__ __forceinline__ unsigned packhi(float f0, float f1) {
    return __builtin_amdgcn_perm(__float_as_uint(f1), __float_as_uint(f0), 0x07060302);
}
__device__ __forceinline__ float hitrunc(float x) {
    return __uint_as_float(__float_as_uint(x) & 0xFFFF0000u);
}
__device__ __forceinline__ ushort bf16bits(float v) {
    __hip_bfloat16 b = __float2bfloat16(v);
    return __builtin_bit_cast(ushort, b);
}

// ---- Kernel 1: MFMA GEMM hp=h@w; tiled-transposed bf16 out + exp factors -----
// grid 1024: block = (b, hd, 64-row tile). 256 thr = 4 waves.
__global__ __launch_bounds__(256) void k_proj(
    const void* __restrict__ h, const void* __restrict__ w,
    const void* __restrict__ asrc, const void* __restrict__ adst,
    ushort* __restrict__ hpTt, float* __restrict__ esHa, float* __restrict__ esLa,
    float* __restrict__ edHa, float* __restrict__ edLa, int* __restrict__ flagOut)
{
    const int t  = threadIdx.x;
    const int rt = blockIdx.x & 31;
    const int hd = (blockIdx.x >> 5) & 7;
    const int b  = blockIdx.x >> 8;
    const int bh = b * NH + hd;
    const int r0 = rt * 64;

    __shared__ int sb16;
    __shared__ ushort SH[4 * 64 * 72];           // bHi | bLo | aHi | aLo (36.9 KB)
    ushort* bHi = SH;
    ushort* bLo = SH + 64 * 72;
    ushort* aHi = SH + 2 * 64 * 72;
    ushort* aLo = SH + 3 * 64 * 72;

    if (t < 64) {
        unsigned word = ((const unsigned*)h)[t];
        unsigned lowexp = (word >> 7) & 0xFFu;
        bool plaus = (lowexp >= 96u && lowexp <= 159u);
        unsigned long long m = __ballot(plaus);
        if (t == 0) sb16 = (__popcll(m) >= 48) ? 1 : 0;
    }
    __syncthreads();
    const int b16 = sb16;
    if (blockIdx.x == 0 && t == 0) flagOut[0] = b16;

    const int lane = t & 63, wv = t >> 6;
    const int ml = lane & 15, q = lane >> 4;

    if (b16) {
        // w[k][n] -> bHi[n][k]: column gather, coalesced in n
        const ushort* wp = (const ushort*)w + (size_t)hd * FF * FF;
        const int n = t & 63, kq4 = (t >> 6) * 4;
#pragma unroll
        for (int g = 0; g < 4; ++g) {
            int kb = g * 16 + kq4;
            ushort v0 = wp[(kb + 0) * FF + n];
            ushort v1 = wp[(kb + 1) * FF + n];
            ushort v2 = wp[(kb + 2) * FF + n];
            ushort v3 = wp[(kb + 3) * FF + n];
            uint2 pk = { (unsigned)v0 | ((unsigned)v1 << 16),
                         (unsigned)v2 | ((unsigned)v3 << 16) };
            *(uint2*)&bHi[n * 72 + kb] = pk;
        }
        const ushort* hsrc = (const ushort*)h + (size_t)(b * NN + r0) * FF;
        for (int g = t; g < 512; g += 256) {
            int row = g >> 3, c8 = (g & 7) * 8;
            uint4v u = *(const uint4v*)(hsrc + row * FF + c8);
            *(uint4v*)&aHi[row * 72 + c8] = u;
        }
    } else {
        const float* wp = (const float*)w + (size_t)hd * FF * FF;
        const int n = t & 63, kq4 = (t >> 6) * 4;
#pragma unroll
        for (int g = 0; g < 4; ++g) {
            int kb = g * 16 + kq4;
            float x0 = wp[(kb + 0) * FF + n];
            float x1 = wp[(kb + 1) * FF + n];
            float x2 = wp[(kb + 2) * FF + n];
            float x3 = wp[(kb + 3) * FF + n];
            uint2 hi2 = { packhi(x0, x1), packhi(x2, x3) };
            uint2 lo2 = { packhi(x0 - hitrunc(x0), x1 - hitrunc(x1)),
                          packhi(x2 - hitrunc(x2), x3 - hitrunc(x3)) };
            *(uint2*)&bHi[n * 72 + kb] = hi2;
            *(uint2*)&bLo[n * 72 + kb] = lo2;
        }
        const float* hsrc = (const float*)h + (size_t)(b * NN + r0) * FF;
        for (int g = t; g < 1024; g += 256) {
            int row = g >> 4, c4 = (g & 15) * 4;
            floatx4 x = *(const floatx4*)(hsrc + row * FF + c4);
            uint2 hi2 = { packhi(x[0], x[1]), packhi(x[2], x[3]) };
            uint2 lo2 = { packhi(x[0] - hitrunc(x[0]), x[1] - hitrunc(x[1])),
                          packhi(x[2] - hitrunc(x[2]), x[3] - hitrunc(x[3])) };
            *(uint2*)&aHi[row * 72 + c4] = hi2;
            *(uint2*)&aLo[row * 72 + c4] = lo2;
        }
    }
    __syncthreads();

    short8 ah[2], al[2];
#pragma unroll
    for (int kc = 0; kc < 2; ++kc) {
        ah[kc] = *(const short8*)&aHi[(wv * 16 + ml) * 72 + kc * 32 + q * 8];
        if (!b16) al[kc] = *(const short8*)&aLo[(wv * 16 + ml) * 72 + kc * 32 + q * 8];
    }
    short8 bhf[4][2], blf[4][2];
#pragma unroll
    for (int nt = 0; nt < 4; ++nt)
#pragma unroll
        for (int kc = 0; kc < 2; ++kc) {
            bhf[nt][kc] = *(const short8*)&bHi[(nt * 16 + ml) * 72 + kc * 32 + q * 8];
            if (!b16) blf[nt][kc] = *(const short8*)&bLo[(nt * 16 + ml) * 72 + kc * 32 + q * 8];
        }

    float aS[4], aD[4];
#pragma unroll
    for (int nt = 0; nt < 4; ++nt) {
        aS[nt] = LDIN(asrc, hd * FF + nt * 16 + ml, b16);
        aD[nt] = LDIN(adst, hd * FF + nt * 16 + ml, b16);
    }

    floatx4 acc[4];
#pragma unroll
    for (int nt = 0; nt < 4; ++nt) {
        floatx4 a = {0.f, 0.f, 0.f, 0.f};
        if (b16) {
#pragma unroll
            for (int kc = 0; kc < 2; ++kc)
                a = __builtin_amdgcn_mfma_f32_16x16x32_bf16(ah[kc], bhf[nt][kc], a, 0, 0, 0);
        } else {
#pragma unroll
            for (int kc = 0; kc < 2; ++kc) {
                a = __builtin_amdgcn_mfma_f32_16x16x32_bf16(ah[kc], bhf[nt][kc], a, 0, 0, 0);
                a = __builtin_amdgcn_mfma_f32_16x16x32_bf16(ah[kc], blf[nt][kc], a, 0, 0, 0);
                a = __builtin_amdgcn_mfma_f32_16x16x32_bf16(al[kc], bhf[nt][kc], a, 0, 0, 0);
            }
        }
        acc[nt] = a;
    }

    __syncthreads();                       // all LDS frag reads complete
    ushort* trans = SH;                    // reuse: trans[o][i_local], stride 72
#pragma unroll
    for (int nt = 0; nt < 4; ++nt) {
        ushort b0 = bf16bits(acc[nt][0]), b1 = bf16bits(acc[nt][1]);
        ushort b2 = bf16bits(acc[nt][2]), b3 = bf16bits(acc[nt][3]);
        uint2 pk = { (unsigned)b0 | ((unsigned)b1 << 16),
                     (unsigned)b2 | ((unsigned)b3 << 16) };
        *(uint2*)&trans[(nt * 16 + ml) * 72 + wv * 16 + q * 4] = pk;
    }

    float ps[4] = {0.f, 0.f, 0.f, 0.f}, pd[4] = {0.f, 0.f, 0.f, 0.f};
#pragma unroll
    for (int nt = 0; nt < 4; ++nt)
#pragma unroll
        for (int reg = 0; reg < 4; ++reg) {
            float tv = tanhf(acc[nt][reg]);
            ps[reg] += tv * aS[nt];
            pd[reg] += tv * aD[nt];
        }
#pragma unroll
    for (int msk = 1; msk < 16; msk <<= 1)
#pragma unroll
        for (int reg = 0; reg < 4; ++reg) {
            ps[reg] += __shfl_xor(ps[reg], msk, 64);
            pd[reg] += __shfl_xor(pd[reg], msk, 64);
        }
    if (ml == 0) {
#pragma unroll
        for (int reg = 0; reg < 4; ++reg) {
            int i = bh * NN + r0 + wv * 16 + q * 4 + reg;
            float sv = ps[reg], dv = pd[reg];
            esHa[i] = __expf(sv);
            esLa[i] = __expf(0.2f * sv);
            edHa[i] = __expf(dv);
            edLa[i] = __expf(0.2f * dv);
        }
    }
    __syncthreads();
    // tiled, fully-coalesced write: hpTt[((bh*32 + rt)*64 + o)*64 + jin]
    {
        const int o = t >> 2, part = (t & 3) * 16;
        uint4v v0 = *(const uint4v*)&trans[o * 72 + part];
        uint4v v1 = *(const uint4v*)&trans[o * 72 + part + 8];
        ushort* dst = hpTt + (((size_t)bh * 32 + rt) * 64 + o) * 64 + part;
        *(uint4v*)dst = v0;
        *(uint4v*)(dst + 8) = v1;
    }
}

// ---- Kernel 2: dense attention, LDS-staged B, 2 i-tiles/wave -----------------
// grid 512: block = (bh, 128-row i-block). 4 waves; wave owns i-tiles wv*16, wv*16+64.
__global__ __launch_bounds__(256) void k_attn(
    const ushort* __restrict__ hpTt,
    const float* __restrict__ esHa, const float* __restrict__ esLa,
    const float* __restrict__ edHa, const float* __restrict__ edLa,
    const void* __restrict__ bias, const int* __restrict__ flag,
    void* __restrict__ out)
{
    const int b16 = flag[0];
    const int t = threadIdx.x;
    const int wv = t >> 6, lane = t & 63;
    const int ml = lane & 15, q = lane >> 4;
    const int bh = blockIdx.x & 31;
    const int ibase = (blockIdx.x >> 5) * 128;
    const int i0 = ibase + wv * 16;

    __shared__ ushort Bc[2][64 * 72];            // 18.4 KB, double-buffered

    const ushort* src = hpTt + (size_t)bh * NN * FF;
    const float* ehp = edHa + bh * NN;
    const float* elp = edLa + bh * NN;

    float es[2], es2[2];
#pragma unroll
    for (int it = 0; it < 2; ++it) {
        es[it]  = esHa[bh * NN + i0 + it * 64 + ml];
        es2[it] = esLa[bh * NN + i0 + it * 64 + ml];
    }

    floatx4 acc[2][4];
#pragma unroll
    for (int it = 0; it < 2; ++it)
#pragma unroll
        for (int nt = 0; nt < 4; ++nt) acc[it][nt] = (floatx4){0.f, 0.f, 0.f, 0.f};
    float den[2] = {0.f, 0.f};

    auto stage = [&](int c, int buf) {
        const ushort* s = src + (size_t)c * 4096 + t * 16;
        uint4v u0 = *(const uint4v*)s;
        uint4v u1 = *(const uint4v*)(s + 8);
        ushort* d = &Bc[buf][(t >> 2) * 72 + (t & 3) * 16];
        *(uint4v*)d = u0;
        *(uint4v*)(d + 8) = u1;
    };

    auto compute = [&](int c, int buf) {
        const int j0 = c * 64;
#pragma unroll
        for (int ks = 0; ks < 2; ++ks) {
            const int col = ks * 32 + q * 8;
            floatx4 eh0 = *(const floatx4*)(ehp + j0 + col);
            floatx4 eh1 = *(const floatx4*)(ehp + j0 + col + 4);
            floatx4 el0 = *(const floatx4*)(elp + j0 + col);
            floatx4 el1 = *(const floatx4*)(elp + j0 + col + 4);
            short8 Bf[4];
#pragma unroll
            for (int nt = 0; nt < 4; ++nt)
                Bf[nt] = *(const short8*)&Bc[buf][(nt * 16 + ml) * 72 + col];
#pragma unroll
            for (int it = 0; it < 2; ++it) {
                float p[8];
#pragma unroll
                for (int j = 0; j < 4; ++j) {
                    p[j]     = fmaxf(es[it] * eh0[j], es2[it] * el0[j]);
                    p[j + 4] = fmaxf(es[it] * eh1[j], es2[it] * el1[j]);
                }
                den[it] += ((p[0] + p[1]) + (p[2] + p[3]))
                         + ((p[4] + p[5]) + (p[6] + p[7]));
                unsigned hw[4], lw[4];
#pragma unroll
                for (int pr = 0; pr < 4; ++pr) {
                    float a0 = p[2 * pr], a1 = p[2 * pr + 1];
                    hw[pr] = packhi(a0, a1);
                    lw[pr] = packhi(a0 - hitrunc(a0), a1 - hitrunc(a1));
                }
                short8 PH = __builtin_bit_cast(short8, (uint4v){hw[0], hw[1], hw[2], hw[3]});
                short8 PL = __builtin_bit_cast(short8, (uint4v){lw[0], lw[1], lw[2], lw[3]});
#pragma unroll
                for (int nt = 0; nt < 4; ++nt) {
                    acc[it][nt] = __builtin_amdgcn_mfma_f32_16x16x32_bf16(PH, Bf[nt], acc[it][nt], 0, 0, 0);
                    acc[it][nt] = __builtin_amdgcn_mfma_f32_16x16x32_bf16(PL, Bf[nt], acc[it][nt], 0, 0, 0);
                }
            }
        }
    };

    stage(0, 0);
    __syncthreads();
    for (int c = 0; c < 32; ++c) {
        const int buf = c & 1;
        if (c < 31) stage(c + 1, buf ^ 1);
        compute(c, buf);
        __syncthreads();
    }

    float biasv[4];
#pragma unroll
    for (int nt = 0; nt < 4; ++nt) biasv[nt] = LDIN(bias, nt * 16 + ml, b16);

#pragma unroll
    for (int it = 0; it < 2; ++it) {
        float d2 = den[it];
        d2 += __shfl_xor(d2, 16, 64);
        d2 += __shfl_xor(d2, 32, 64);            // lanes hold den[row = ml]
#pragma unroll
        for (int reg = 0; reg < 4; ++reg) {
            float dr = __shfl(d2, q * 4 + reg, 64);
            float inv = 1.0f / dr;
            int i = i0 + it * 64 + q * 4 + reg;
#pragma unroll
            for (int nt = 0; nt < 4; ++nt) {
                float val = acc[it][nt][reg] * inv + biasv[nt];
                size_t oi = ((size_t)bh * NN + i) * FF + nt * 16 + ml;
                if (b16) ((__hip_bfloat16*)out)[oi] = __float2bfloat16(val);
                else     ((float*)out)[oi] = val;
            }
        }
    }
}

extern "C" void kernel_launch(void* const* d_in, const int* in_sizes, int n_in,
                              void* d_out, int out_size, void* d_ws, size_t ws_size,
                              hipStream_t stream) {
    const void* h    = d_in[0];
    // d_in[1] = adj (bool) — unused by reference
    const void* w    = d_in[2];
    const void* asrc = d_in[3];
    const void* adst = d_in[4];
    const void* bias = d_in[5];

    float* ws = (float*)d_ws;
    int*    flag = (int*)ws;                            // 16 ints
    ushort* hpTt = (ushort*)(ws + 16);                  // BH*NN*FF bf16, tiled
    float*  esHa = (float*)(hpTt + (size_t)BH * NN * FF);
    float*  esLa = esHa + BH * NN;
    float*  edHa = esLa + BH * NN;
    float*  edLa = edHa + BH * NN;

    k_proj<<<BDIM * NH * 32, 256, 0, stream>>>(h, w, asrc, adst,
                                               hpTt, esHa, esLa, edHa, edLa, flag);
    k_attn<<<BH * 16, 256, 0, stream>>>(hpTt, esHa, esLa, edHa, edLa,
                                        bias, flag, d_out);
}

// Round 10
// 139.760 us; speedup vs baseline: 1.8213x; 1.1558x over previous
//
#include <hip/hip_runtime.h>
#include <hip/hip_bf16.h>

#define NN 2048
#define FF 64
#define NH 8
#define BDIM 4
#define BH 32        // BDIM*NH

typedef __attribute__((ext_vector_type(8))) short short8;
typedef __attribute__((ext_vector_type(4))) float floatx4;
typedef __attribute__((ext_vector_type(4))) unsigned uint4v;

__device__ __forceinline__ float LDIN(const void* p, size_t i, int b16) {
    return b16 ? __bfloat162float(((const __hip_bfloat16*)p)[i]) : ((const float*)p)[i];
}
// pack bf16(truncate) of f0 (low) and f1 (high) into one uint
__device__ __forceinline__ unsigned packhi(float f0, float f1) {
    return __builtin_amdgcn_perm(__float_as_uint(f1), __float_as_uint(f0), 0x07060302);
}
__device__ __forceinline__ float hitrunc(float x) {
    return __uint_as_float(__float_as_uint(x) & 0xFFFF0000u);
}
__device__ __forceinline__ ushort bf16bits(float v) {
    __hip_bfloat16 b = __float2bfloat16(v);
    return __builtin_bit_cast(ushort, b);
}
// XOR-swizzled LDS index (stride 64 shorts, 8-short groups). col must be 4-aligned.
__device__ __forceinline__ int SWZ(int row, int col) {
    return row * 64 + ((((col >> 3) ^ (row & 7)) << 3) | (col & 7));
}
__device__ __forceinline__ float fast_tanh(float v) {
    float ex = __expf(2.0f * v);
    return 1.0f - 2.0f * __builtin_amdgcn_rcpf(ex + 1.0f);
}

// ---- Kernel 1: MFMA GEMM hp=h@w; tiled-transposed bf16 out + r/edH/edL -------
// grid 1024: block = (b, hd, 64-row tile). 256 thr = 4 waves.
__global__ __launch_bounds__(256) void k_proj(
    const void* __restrict__ h, const void* __restrict__ w,
    const void* __restrict__ asrc, const void* __restrict__ adst,
    ushort* __restrict__ hpTt, float* __restrict__ rArr,
    float* __restrict__ edHa, float* __restrict__ edLa, int* __restrict__ flagOut)
{
    const int t  = threadIdx.x;
    const int rt = blockIdx.x & 31;
    const int hd = (blockIdx.x >> 5) & 7;
    const int b  = blockIdx.x >> 8;
    const int bh = b * NH + hd;
    const int r0 = rt * 64;

    __shared__ int sb16;
    __shared__ ushort SH[4 * 64 * 64];           // bHi | bLo | aHi | aLo (32 KB)
    ushort* bHi = SH;
    ushort* bLo = SH + 64 * 64;
    ushort* aHi = SH + 2 * 64 * 64;
    ushort* aLo = SH + 3 * 64 * 64;

    if (t < 64) {
        unsigned word = ((const unsigned*)h)[t];
        unsigned lowexp = (word >> 7) & 0xFFu;
        bool plaus = (lowexp >= 96u && lowexp <= 159u);
        unsigned long long m = __ballot(plaus);
        if (t == 0) sb16 = (__popcll(m) >= 48) ? 1 : 0;
    }
    __syncthreads();
    const int b16 = sb16;
    if (blockIdx.x == 0 && t == 0) flagOut[0] = b16;

    const int lane = t & 63, wv = t >> 6;
    const int ml = lane & 15, q = lane >> 4;

    if (b16) {
        const ushort* wp = (const ushort*)w + (size_t)hd * FF * FF;
        const int n = t & 63, kq4 = (t >> 6) * 4;
#pragma unroll
        for (int g = 0; g < 4; ++g) {
            int kb = g * 16 + kq4;
            ushort v0 = wp[(kb + 0) * FF + n];
            ushort v1 = wp[(kb + 1) * FF + n];
            ushort v2 = wp[(kb + 2) * FF + n];
            ushort v3 = wp[(kb + 3) * FF + n];
            uint2 pk = { (unsigned)v0 | ((unsigned)v1 << 16),
                         (unsigned)v2 | ((unsigned)v3 << 16) };
            *(uint2*)&bHi[SWZ(n, kb)] = pk;
        }
        const ushort* hsrc = (const ushort*)h + (size_t)(b * NN + r0) * FF;
        for (int g = t; g < 512; g += 256) {
            int row = g >> 3, c8 = (g & 7) * 8;
            uint4v u = *(const uint4v*)(hsrc + row * FF + c8);
            *(uint4v*)&aHi[SWZ(row, c8)] = u;
        }
    } else {
        const float* wp = (const float*)w + (size_t)hd * FF * FF;
        const int n = t & 63, kq4 = (t >> 6) * 4;
#pragma unroll
        for (int g = 0; g < 4; ++g) {
            int kb = g * 16 + kq4;
            float x0 = wp[(kb + 0) * FF + n];
            float x1 = wp[(kb + 1) * FF + n];
            float x2 = wp[(kb + 2) * FF + n];
            float x3 = wp[(kb + 3) * FF + n];
            uint2 hi2 = { packhi(x0, x1), packhi(x2, x3) };
            uint2 lo2 = { packhi(x0 - hitrunc(x0), x1 - hitrunc(x1)),
                          packhi(x2 - hitrunc(x2), x3 - hitrunc(x3)) };
            *(uint2*)&bHi[SWZ(n, kb)] = hi2;
            *(uint2*)&bLo[SWZ(n, kb)] = lo2;
        }
        const float* hsrc = (const float*)h + (size_t)(b * NN + r0) * FF;
        for (int g = t; g < 1024; g += 256) {
            int row = g >> 4, c4 = (g & 15) * 4;
            floatx4 x = *(const floatx4*)(hsrc + row * FF + c4);
            uint2 hi2 = { packhi(x[0], x[1]), packhi(x[2], x[3]) };
            uint2 lo2 = { packhi(x[0] - hitrunc(x[0]), x[1] - hitrunc(x[1])),
                          packhi(x[2] - hitrunc(x[2]), x[3] - hitrunc(x[3])) };
            *(uint2*)&aHi[SWZ(row, c4)] = hi2;
            *(uint2*)&aLo[SWZ(row, c4)] = lo2;
        }
    }
    __syncthreads();

    short8 ah[2], al[2];
#pragma unroll
    for (int kc = 0; kc < 2; ++kc) {
        ah[kc] = *(const short8*)&aHi[SWZ(wv * 16 + ml, kc * 32 + q * 8)];
        if (!b16) al[kc] = *(const short8*)&aLo[SWZ(wv * 16 + ml, kc * 32 + q * 8)];
    }
    short8 bhf[4][2], blf[4][2];
#pragma unroll
    for (int nt = 0; nt < 4; ++nt)
#pragma unroll
        for (int kc = 0; kc < 2; ++kc) {
            bhf[nt][kc] = *(const short8*)&bHi[SWZ(nt * 16 + ml, kc * 32 + q * 8)];
            if (!b16) blf[nt][kc] = *(const short8*)&bLo[SWZ(nt * 16 + ml, kc * 32 + q * 8)];
        }

    float aS[4], aD[4];
#pragma unroll
    for (int nt = 0; nt < 4; ++nt) {
        aS[nt] = LDIN(asrc, hd * FF + nt * 16 + ml, b16);
        aD[nt] = LDIN(adst, hd * FF + nt * 16 + ml, b16);
    }

    floatx4 acc[4];
#pragma unroll
    for (int nt = 0; nt < 4; ++nt) {
        floatx4 a = {0.f, 0.f, 0.f, 0.f};
        if (b16) {
#pragma unroll
            for (int kc = 0; kc < 2; ++kc)
                a = __builtin_amdgcn_mfma_f32_16x16x32_bf16(ah[kc], bhf[nt][kc], a, 0, 0, 0);
        } else {
#pragma unroll
            for (int kc = 0; kc < 2; ++kc) {
                a = __builtin_amdgcn_mfma_f32_16x16x32_bf16(ah[kc], bhf[nt][kc], a, 0, 0, 0);
                a = __builtin_amdgcn_mfma_f32_16x16x32_bf16(ah[kc], blf[nt][kc], a, 0, 0, 0);
                a = __builtin_amdgcn_mfma_f32_16x16x32_bf16(al[kc], bhf[nt][kc], a, 0, 0, 0);
            }
        }
        acc[nt] = a;
    }

    __syncthreads();                       // all LDS frag reads complete
    ushort* trans = SH;                    // reuse: trans[o][i_local], swizzled
#pragma unroll
    for (int nt = 0; nt < 4; ++nt) {
        ushort b0 = bf16bits(acc[nt][0]), b1 = bf16bits(acc[nt][1]);
        ushort b2 = bf16bits(acc[nt][2]), b3 = bf16bits(acc[nt][3]);
        uint2 pk = { (unsigned)b0 | ((unsigned)b1 << 16),
                     (unsigned)b2 | ((unsigned)b3 << 16) };
        *(uint2*)&trans[SWZ(nt * 16 + ml, wv * 16 + q * 4)] = pk;
    }

    float ps[4] = {0.f, 0.f, 0.f, 0.f}, pd[4] = {0.f, 0.f, 0.f, 0.f};
#pragma unroll
    for (int nt = 0; nt < 4; ++nt)
#pragma unroll
        for (int reg = 0; reg < 4; ++reg) {
            float tv = fast_tanh(acc[nt][reg]);
            ps[reg] += tv * aS[nt];
            pd[reg] += tv * aD[nt];
        }
#pragma unroll
    for (int msk = 1; msk < 16; msk <<= 1)
#pragma unroll
        for (int reg = 0; reg < 4; ++reg) {
            ps[reg] += __shfl_xor(ps[reg], msk, 64);
            pd[reg] += __shfl_xor(pd[reg], msk, 64);
        }
    if (ml == 0) {
#pragma unroll
        for (int reg = 0; reg < 4; ++reg) {
            int i = bh * NN + r0 + wv * 16 + q * 4 + reg;
            float sv = ps[reg], dv = pd[reg];
            rArr[i] = __expf(-0.8f * sv);
            edHa[i] = __expf(dv);
            edLa[i] = __expf(0.2f * dv);
        }
    }
    __syncthreads();
    // tiled, fully-coalesced write: hpTt[((bh*32 + rt)*64 + o)*64 + jin]
    {
        const int o = t >> 2, part = (t & 3) * 16;
        uint4v v0 = *(const uint4v*)&trans[SWZ(o, part)];
        uint4v v1 = *(const uint4v*)&trans[SWZ(o, part + 8)];
        ushort* dst = hpTt + (((size_t)bh * 32 + rt) * 64 + o) * 64 + part;
        *(uint4v*)dst = v0;
        *(uint4v*)(dst + 8) = v1;
    }
}

// ---- Kernel 2: dense attention. p = max(eh, r*el); PH-only; den via MFMA-ones.
// grid 512: block = (bh, 128-row i-block), 512 thr = 8 waves, 1 i-tile/wave.
__global__ __launch_bounds__(512) void k_attn(
    const ushort* __restrict__ hpTt, const float* __restrict__ rArr,
    const float* __restrict__ edHa, const float* __restrict__ edLa,
    const void* __restrict__ bias, const int* __restrict__ flag,
    void* __restrict__ out)
{
    const int b16 = flag[0];
    const int t = threadIdx.x;
    const int wv = t >> 6, lane = t & 63;
    const int ml = lane & 15, q = lane >> 4;
    const int bh = blockIdx.x & 31;
    const int i0 = (blockIdx.x >> 5) * 128 + wv * 16;

    __shared__ ushort Bc[2][64 * 64];            // 16 KB, double-buffered, swizzled
    __shared__ __align__(16) float ehS[NN];      // 8 KB
    __shared__ __align__(16) float elS[NN];      // 8 KB

    // stage eh/el once (512 float4 loads, one per thread)
    ((floatx4*)ehS)[t] = ((const floatx4*)(edHa + bh * NN))[t];
    ((floatx4*)elS)[t] = ((const floatx4*)(edLa + bh * NN))[t];

    const ushort* src = hpTt + (size_t)bh * NN * FF;
    const float r = rArr[bh * NN + i0 + ml];     // this lane's P-row factor

    const short8 ONESB = {0x3F80, 0x3F80, 0x3F80, 0x3F80,
                          0x3F80, 0x3F80, 0x3F80, 0x3F80};   // bf16 1.0 ×8

    floatx4 acc[4];
#pragma unroll
    for (int nt = 0; nt < 4; ++nt) acc[nt] = (floatx4){0.f, 0.f, 0.f, 0.f};
    floatx4 accD = {0.f, 0.f, 0.f, 0.f};

    auto stage = [&](int c, int buf) {
        uint4v u = *(const uint4v*)(src + (size_t)c * 4096 + t * 8);
        *(uint4v*)&Bc[buf][SWZ(t >> 3, (t & 7) * 8)] = u;
    };

    auto compute = [&](int c, int buf) {
        const int j0 = c * 64;
#pragma unroll
        for (int ks = 0; ks < 2; ++ks) {
            const int col = ks * 32 + q * 8;
            floatx4 eh0 = *(const floatx4*)&ehS[j0 + col];
            floatx4 eh1 = *(const floatx4*)&ehS[j0 + col + 4];
            floatx4 el0 = *(const floatx4*)&elS[j0 + col];
            floatx4 el1 = *(const floatx4*)&elS[j0 + col + 4];
            short8 Bf[4];
#pragma unroll
            for (int nt = 0; nt < 4; ++nt)
                Bf[nt] = *(const short8*)&Bc[buf][SWZ(nt * 16 + ml, col)];
            float p[8];
#pragma unroll
            for (int j = 0; j < 4; ++j) {
                p[j]     = fmaxf(eh0[j], r * el0[j]);
                p[j + 4] = fmaxf(eh1[j], r * el1[j]);
            }
            uint4v hv = { packhi(p[0], p[1]), packhi(p[2], p[3]),
                          packhi(p[4], p[5]), packhi(p[6], p[7]) };
            short8 PH = __builtin_bit_cast(short8, hv);
#pragma unroll
            for (int nt = 0; nt < 4; ++nt)
                acc[nt] = __builtin_amdgcn_mfma_f32_16x16x32_bf16(PH, Bf[nt], acc[nt], 0, 0, 0);
            accD = __builtin_amdgcn_mfma_f32_16x16x32_bf16(PH, ONESB, accD, 0, 0, 0);
        }
    };

    stage(0, 0);
    __syncthreads();
    for (int c = 0; c < 32; ++c) {
        const int buf = c & 1;
        if (c < 31) stage(c + 1, buf ^ 1);
        compute(c, buf);
        __syncthreads();
    }

    float biasv[4];
#pragma unroll
    for (int nt = 0; nt < 4; ++nt) biasv[nt] = LDIN(bias, nt * 16 + ml, b16);

#pragma unroll
    for (int reg = 0; reg < 4; ++reg) {
        // acc/accD C/D rows are q*4+reg; accD cols all equal that row's denominator
        float inv = 1.0f / accD[reg];
        int i = i0 + q * 4 + reg;
#pragma unroll
        for (int nt = 0; nt < 4; ++nt) {
            float val = acc[nt][reg] * inv + biasv[nt];
            size_t oi = ((size_t)bh * NN + i) * FF + nt * 16 + ml;
            if (b16) ((__hip_bfloat16*)out)[oi] = __float2bfloat16(val);
            else     ((float*)out)[oi] = val;
        }
    }
}

extern "C" void kernel_launch(void* const* d_in, const int* in_sizes, int n_in,
                              void* d_out, int out_size, void* d_ws, size_t ws_size,
                              hipStream_t stream) {
    const void* h    = d_in[0];
    // d_in[1] = adj (bool) — unused by reference
    const void* w    = d_in[2];
    const void* asrc = d_in[3];
    const void* adst = d_in[4];
    const void* bias = d_in[5];

    float* ws = (float*)d_ws;
    int*    flag = (int*)ws;                            // 16 ints
    ushort* hpTt = (ushort*)(ws + 16);                  // BH*NN*FF bf16, tiled
    float*  rArr = (float*)(hpTt + (size_t)BH * NN * FF);
    float*  edHa = rArr + BH * NN;
    float*  edLa = edHa + BH * NN;

    k_proj<<<BDIM * NH * 32, 256, 0, stream>>>(h, w, asrc, adst,
                                               hpTt, rArr, edHa, edLa, flag);
    k_attn<<<BH * 16, 512, 0, stream>>>(hpTt, rArr, edHa, edLa,
                                        bias, flag, d_out);
}

// Round 11
// 138.750 us; speedup vs baseline: 1.8346x; 1.0073x over previous
//
#include <hip/hip_runtime.h>
#include <hip/hip_bf16.h>

#define NN 2048
#define FF 64
#define NH 8
#define BDIM 4
#define BH 32        // BDIM*NH

typedef __attribute__((ext_vector_type(8))) short short8;
typedef __attribute__((ext_vector_type(4))) float floatx4;
typedef __attribute__((ext_vector_type(4))) unsigned uint4v;

__device__ __forceinline__ float LDIN(const void* p, size_t i, int b16) {
    return b16 ? __bfloat162float(((const __hip_bfloat16*)p)[i]) : ((const float*)p)[i];
}
__device__ __forceinline__ unsigned packhi(float f0, float f1) {
    return __builtin_amdgcn_perm(__float_as_uint(f1), __float_as_uint(f0), 0x07060302);
}
__device__ __forceinline__ float hitrunc(float x) {
    return __uint_as_float(__float_as_uint(x) & 0xFFFF0000u);
}
__device__ __forceinline__ ushort bf16bits(float v) {
    __hip_bfloat16 b = __float2bfloat16(v);
    return __builtin_bit_cast(ushort, b);
}
// XOR-swizzled LDS index (stride 64 shorts, 8-short groups). col must be 4-aligned.
__device__ __forceinline__ int SWZ(int row, int col) {
    return row * 64 + ((((col >> 3) ^ (row & 7)) << 3) | (col & 7));
}
__device__ __forceinline__ float fast_tanh(float v) {
    float ex = __expf(2.0f * v);
    return 1.0f - 2.0f * __builtin_amdgcn_rcpf(ex + 1.0f);
}
__device__ __forceinline__ int sniff_b16(const void* h) {
    // wave 0 only; returns via readfirstlane-uniform value
    unsigned word = ((const unsigned*)h)[threadIdx.x & 63];
    unsigned lowexp = (word >> 7) & 0xFFu;
    bool plaus = (lowexp >= 96u && lowexp <= 159u);
    unsigned long long m = __ballot(plaus);
    return (__popcll(m) >= 48) ? 1 : 0;
}

// ---- Kernel 0: one-time w fragmentization -----------------------------------
// grid 8 (one per head) x 256. Writes wF: hi at [hd*4096 + ((nt*2+kc)*4+q)*128 + ml*8],
// lo at +32768. Also writes flag.
__global__ __launch_bounds__(256) void k_prep(
    const void* __restrict__ h, const void* __restrict__ w,
    ushort* __restrict__ wF, int* __restrict__ flagOut)
{
    const int hd = blockIdx.x, t = threadIdx.x;
    __shared__ int sb16;
    if (t < 64) {
        int f = sniff_b16(h);
        if (t == 0) { sb16 = f; if (hd == 0) flagOut[0] = f; }
    }
    __syncthreads();
    const int b16 = sb16;

#pragma unroll
    for (int g = 0; g < 2; ++g) {
        int gi = t * 2 + g;                    // [0,512)
        int ml = gi & 15, q = (gi >> 4) & 3, kc = (gi >> 6) & 1, nt = (gi >> 7) & 3;
        int n = nt * 16 + ml, kb = kc * 32 + q * 8;
        size_t off = (size_t)hd * 4096 + ((nt * 2 + kc) * 4 + q) * 128 + ml * 8;
        if (b16) {
            const ushort* wp = (const ushort*)w + (size_t)hd * FF * FF;
            ushort hi[8];
#pragma unroll
            for (int j = 0; j < 8; ++j) hi[j] = wp[(kb + j) * FF + n];
            *(uint4v*)&wF[off] = __builtin_bit_cast(uint4v, *(short8*)hi);
            short8 z = {0, 0, 0, 0, 0, 0, 0, 0};
            *(uint4v*)&wF[off + 32768] = __builtin_bit_cast(uint4v, z);
        } else {
            const float* wp = (const float*)w + (size_t)hd * FF * FF;
            float x[8];
#pragma unroll
            for (int j = 0; j < 8; ++j) x[j] = wp[(kb + j) * FF + n];
            uint4v hv = { packhi(x[0], x[1]), packhi(x[2], x[3]),
                          packhi(x[4], x[5]), packhi(x[6], x[7]) };
            uint4v lv = { packhi(x[0] - hitrunc(x[0]), x[1] - hitrunc(x[1])),
                          packhi(x[2] - hitrunc(x[2]), x[3] - hitrunc(x[3])),
                          packhi(x[4] - hitrunc(x[4]), x[5] - hitrunc(x[5])),
                          packhi(x[6] - hitrunc(x[6]), x[7] - hitrunc(x[7])) };
            *(uint4v*)&wF[off] = hv;
            *(uint4v*)&wF[off + 32768] = lv;
        }
    }
}

// ---- Kernel 1: MFMA GEMM hp=h@w; tiled-transposed bf16 out + r/edH/edL -------
// grid 1024: block = (b, hd, 64-row tile). 256 thr = 4 waves.
__global__ __launch_bounds__(256) void k_proj(
    const void* __restrict__ h, const ushort* __restrict__ wF,
    const void* __restrict__ asrc, const void* __restrict__ adst,
    ushort* __restrict__ hpTt, float* __restrict__ rArr,
    float* __restrict__ edHa, float* __restrict__ edLa)
{
    const int t  = threadIdx.x;
    const int rt = blockIdx.x & 31;
    const int hd = (blockIdx.x >> 5) & 7;
    const int b  = blockIdx.x >> 8;
    const int bh = b * NH + hd;
    const int r0 = rt * 64;

    __shared__ int sb16;
    __shared__ ushort aHi[64 * 64];
    __shared__ ushort aLo[64 * 64];
    __shared__ ushort trans[64 * 64];
    if (t < 64) {
        int f = sniff_b16(h);
        if (t == 0) sb16 = f;
    }
    __syncthreads();
    const int b16 = sb16;

    const int lane = t & 63, wv = t >> 6;
    const int ml = lane & 15, q = lane >> 4;

    if (b16) {
        const ushort* hsrc = (const ushort*)h + (size_t)(b * NN + r0) * FF;
#pragma unroll
        for (int g0 = 0; g0 < 2; ++g0) {
            int g = t + g0 * 256;
            int row = g >> 3, c8 = (g & 7) * 8;
            uint4v u = *(const uint4v*)(hsrc + row * FF + c8);
            *(uint4v*)&aHi[SWZ(row, c8)] = u;
        }
    } else {
        const float* hsrc = (const float*)h + (size_t)(b * NN + r0) * FF;
#pragma unroll
        for (int g0 = 0; g0 < 4; ++g0) {
            int g = t + g0 * 256;
            int row = g >> 4, c4 = (g & 15) * 4;
            floatx4 x = *(const floatx4*)(hsrc + row * FF + c4);
            uint2 hi2 = { packhi(x[0], x[1]), packhi(x[2], x[3]) };
            uint2 lo2 = { packhi(x[0] - hitrunc(x[0]), x[1] - hitrunc(x[1])),
                          packhi(x[2] - hitrunc(x[2]), x[3] - hitrunc(x[3])) };
            *(uint2*)&aHi[SWZ(row, c4)] = hi2;
            *(uint2*)&aLo[SWZ(row, c4)] = lo2;
        }
    }
    __syncthreads();

    short8 ah[2], al[2];
#pragma unroll
    for (int kc = 0; kc < 2; ++kc) {
        ah[kc] = *(const short8*)&aHi[SWZ(wv * 16 + ml, kc * 32 + q * 8)];
        if (!b16) al[kc] = *(const short8*)&aLo[SWZ(wv * 16 + ml, kc * 32 + q * 8)];
    }
    // B fragments: coalesced 16B/lane from fragment-major global layout (L2-hot)
    short8 bhf[4][2], blf[4][2];
    const ushort* wfh = wF + (size_t)hd * 4096;
#pragma unroll
    for (int nt = 0; nt < 4; ++nt)
#pragma unroll
        for (int kc = 0; kc < 2; ++kc) {
            size_t off = ((nt * 2 + kc) * 4 + q) * 128 + ml * 8;
            bhf[nt][kc] = __builtin_bit_cast(short8, *(const uint4v*)&wfh[off]);
            if (!b16) blf[nt][kc] = __builtin_bit_cast(short8, *(const uint4v*)&wfh[off + 32768]);
        }

    float aS[4], aD[4];
#pragma unroll
    for (int nt = 0; nt < 4; ++nt) {
        aS[nt] = LDIN(asrc, hd * FF + nt * 16 + ml, b16);
        aD[nt] = LDIN(adst, hd * FF + nt * 16 + ml, b16);
    }

    floatx4 acc[4];
#pragma unroll
    for (int nt = 0; nt < 4; ++nt) {
        floatx4 a = {0.f, 0.f, 0.f, 0.f};
        if (b16) {
#pragma unroll
            for (int kc = 0; kc < 2; ++kc)
                a = __builtin_amdgcn_mfma_f32_16x16x32_bf16(ah[kc], bhf[nt][kc], a, 0, 0, 0);
        } else {
#pragma unroll
            for (int kc = 0; kc < 2; ++kc) {
                a = __builtin_amdgcn_mfma_f32_16x16x32_bf16(ah[kc], bhf[nt][kc], a, 0, 0, 0);
                a = __builtin_amdgcn_mfma_f32_16x16x32_bf16(ah[kc], blf[nt][kc], a, 0, 0, 0);
                a = __builtin_amdgcn_mfma_f32_16x16x32_bf16(al[kc], bhf[nt][kc], a, 0, 0, 0);
            }
        }
        acc[nt] = a;
    }

    // transposed tile staging (separate buffer — no barrier needed before writes)
#pragma unroll
    for (int nt = 0; nt < 4; ++nt) {
        ushort b0 = bf16bits(acc[nt][0]), b1 = bf16bits(acc[nt][1]);
        ushort b2 = bf16bits(acc[nt][2]), b3 = bf16bits(acc[nt][3]);
        uint2 pk = { (unsigned)b0 | ((unsigned)b1 << 16),
                     (unsigned)b2 | ((unsigned)b3 << 16) };
        *(uint2*)&trans[SWZ(nt * 16 + ml, wv * 16 + q * 4)] = pk;
    }

    float ps[4] = {0.f, 0.f, 0.f, 0.f}, pd[4] = {0.f, 0.f, 0.f, 0.f};
#pragma unroll
    for (int nt = 0; nt < 4; ++nt)
#pragma unroll
        for (int reg = 0; reg < 4; ++reg) {
            float tv = fast_tanh(acc[nt][reg]);
            ps[reg] += tv * aS[nt];
            pd[reg] += tv * aD[nt];
        }
#pragma unroll
    for (int msk = 1; msk < 16; msk <<= 1)
#pragma unroll
        for (int reg = 0; reg < 4; ++reg) {
            ps[reg] += __shfl_xor(ps[reg], msk, 64);
            pd[reg] += __shfl_xor(pd[reg], msk, 64);
        }
    if (ml == 0) {
#pragma unroll
        for (int reg = 0; reg < 4; ++reg) {
            int i = bh * NN + r0 + wv * 16 + q * 4 + reg;
            float sv = ps[reg], dv = pd[reg];
            rArr[i] = __expf(-0.8f * sv);
            edHa[i] = __expf(dv);
            edLa[i] = __expf(0.2f * dv);
        }
    }
    __syncthreads();
    // tiled, fully-coalesced write: hpTt[((bh*32 + rt)*64 + o)*64 + jin]
    {
        const int o = t >> 2, part = (t & 3) * 16;
        uint4v v0 = *(const uint4v*)&trans[SWZ(o, part)];
        uint4v v1 = *(const uint4v*)&trans[SWZ(o, part + 8)];
        ushort* dst = hpTt + (((size_t)bh * 32 + rt) * 64 + o) * 64 + part;
        *(uint4v*)dst = v0;
        *(uint4v*)(dst + 8) = v1;
    }
}

// ---- Kernel 2: dense attention. p = max(eh, r*el); PH-only; den via MFMA-ones.
// grid 512: block = (bh, 128-row i-block), 512 thr = 8 waves, 1 i-tile/wave.
// 4-way LDS buffer: 2 chunks staged per barrier (16 barriers total).
__global__ __launch_bounds__(512) void k_attn(
    const ushort* __restrict__ hpTt, const float* __restrict__ rArr,
    const float* __restrict__ edHa, const float* __restrict__ edLa,
    const void* __restrict__ bias, const int* __restrict__ flag,
    void* __restrict__ out)
{
    const int b16 = flag[0];
    const int t = threadIdx.x;
    const int wv = t >> 6, lane = t & 63;
    const int ml = lane & 15, q = lane >> 4;
    const int bh = blockIdx.x & 31;
    const int i0 = (blockIdx.x >> 5) * 128 + wv * 16;

    __shared__ ushort Bc[4][64 * 64];            // 32 KB, 4-way, swizzled
    __shared__ __align__(16) float ehS[NN];      // 8 KB
    __shared__ __align__(16) float elS[NN];      // 8 KB

    ((floatx4*)ehS)[t] = ((const floatx4*)(edHa + bh * NN))[t];
    ((floatx4*)elS)[t] = ((const floatx4*)(edLa + bh * NN))[t];

    const ushort* src = hpTt + (size_t)bh * NN * FF;
    const float r = rArr[bh * NN + i0 + ml];     // this lane's P-row factor

    const short8 ONESB = {0x3F80, 0x3F80, 0x3F80, 0x3F80,
                          0x3F80, 0x3F80, 0x3F80, 0x3F80};   // bf16 1.0 ×8

    floatx4 acc[4];
#pragma unroll
    for (int nt = 0; nt < 4; ++nt) acc[nt] = (floatx4){0.f, 0.f, 0.f, 0.f};
    floatx4 accD = {0.f, 0.f, 0.f, 0.f};

    auto stage = [&](int c) {
        uint4v u = *(const uint4v*)(src + (size_t)c * 4096 + t * 8);
        *(uint4v*)&Bc[c & 3][SWZ(t >> 3, (t & 7) * 8)] = u;
    };

    auto compute = [&](int c) {
        const int j0 = c * 64, buf = c & 3;
#pragma unroll
        for (int ks = 0; ks < 2; ++ks) {
            const int col = ks * 32 + q * 8;
            floatx4 eh0 = *(const floatx4*)&ehS[j0 + col];
            floatx4 eh1 = *(const floatx4*)&ehS[j0 + col + 4];
            floatx4 el0 = *(const floatx4*)&elS[j0 + col];
            floatx4 el1 = *(const floatx4*)&elS[j0 + col + 4];
            short8 Bf[4];
#pragma unroll
            for (int nt = 0; nt < 4; ++nt)
                Bf[nt] = *(const short8*)&Bc[buf][SWZ(nt * 16 + ml, col)];
            float p[8];
#pragma unroll
            for (int j = 0; j < 4; ++j) {
                p[j]     = fmaxf(eh0[j], r * el0[j]);
                p[j + 4] = fmaxf(eh1[j], r * el1[j]);
            }
            uint4v hv = { packhi(p[0], p[1]), packhi(p[2], p[3]),
                          packhi(p[4], p[5]), packhi(p[6], p[7]) };
            short8 PH = __builtin_bit_cast(short8, hv);
#pragma unroll
            for (int nt = 0; nt < 4; ++nt)
                acc[nt] = __builtin_amdgcn_mfma_f32_16x16x32_bf16(PH, Bf[nt], acc[nt], 0, 0, 0);
            accD = __builtin_amdgcn_mfma_f32_16x16x32_bf16(PH, ONESB, accD, 0, 0, 0);
        }
    };

    stage(0); stage(1);
    __syncthreads();
    for (int c = 0; c < 32; c += 2) {
        if (c + 2 < 32) { stage(c + 2); stage(c + 3); }
        compute(c);
        compute(c + 1);
        __syncthreads();
    }

    float biasv[4];
#pragma unroll
    for (int nt = 0; nt < 4; ++nt) biasv[nt] = LDIN(bias, nt * 16 + ml, b16);

#pragma unroll
    for (int reg = 0; reg < 4; ++reg) {
        float inv = 1.0f / accD[reg];
        int i = i0 + q * 4 + reg;
#pragma unroll
        for (int nt = 0; nt < 4; ++nt) {
            float val = acc[nt][reg] * inv + biasv[nt];
            size_t oi = ((size_t)bh * NN + i) * FF + nt * 16 + ml;
            if (b16) ((__hip_bfloat16*)out)[oi] = __float2bfloat16(val);
            else     ((float*)out)[oi] = val;
        }
    }
}

extern "C" void kernel_launch(void* const* d_in, const int* in_sizes, int n_in,
                              void* d_out, int out_size, void* d_ws, size_t ws_size,
                              hipStream_t stream) {
    const void* h    = d_in[0];
    // d_in[1] = adj (bool) — unused by reference
    const void* w    = d_in[2];
    const void* asrc = d_in[3];
    const void* adst = d_in[4];
    const void* bias = d_in[5];

    float* ws = (float*)d_ws;
    int*    flag = (int*)ws;                            // 16 ints
    ushort* hpTt = (ushort*)(ws + 16);                  // BH*NN*FF bf16, tiled
    float*  rArr = (float*)(hpTt + (size_t)BH * NN * FF);
    float*  edHa = rArr + BH * NN;
    float*  edLa = edHa + BH * NN;
    ushort* wF   = (ushort*)(edLa + BH * NN);           // 65536 shorts (hi|lo)

    k_prep<<<NH, 256, 0, stream>>>(h, w, wF, flag);
    k_proj<<<BDIM * NH * 32, 256, 0, stream>>>(h, wF, asrc, adst,
                                               hpTt, rArr, edHa, edLa);
    k_attn<<<BH * 16, 512, 0, stream>>>(hpTt, rArr, edHa, edLa,
                                        bias, flag, d_out);
}